// Round 5
// baseline (613.773 us; speedup 1.0000x reference)
//
#include <hip/hip_runtime.h>

// Problem constants (fixed by reference)
constexpr int B_ROWS = 65536;
constexpr int IN_F   = 1024;
constexpr int OUT_F  = 1024;

constexpr int BDIM = 512;            // 8 waves
constexpr int BM = 256, BN = 256, BK = 64;

typedef __bf16 bf16x8 __attribute__((ext_vector_type(8)));
typedef float  f32x4  __attribute__((ext_vector_type(4)));

__device__ __forceinline__ bf16x8 cvt8(f32x4 u0, f32x4 u1) {
    bf16x8 v;
    v[0] = (__bf16)u0[0]; v[1] = (__bf16)u0[1]; v[2] = (__bf16)u0[2]; v[3] = (__bf16)u0[3];
    v[4] = (__bf16)u1[0]; v[5] = (__bf16)u1[1]; v[6] = (__bf16)u1[2]; v[7] = (__bf16)u1[3];
    return v;
}

// async global->LDS, 16B per lane (wave stages 1KB contiguous at uniform lds base)
__device__ __forceinline__ void glds16(const __bf16* g, unsigned char* l) {
    __builtin_amdgcn_global_load_lds(
        (const __attribute__((address_space(1))) unsigned int*)(const void*)g,
        (__attribute__((address_space(3))) unsigned int*)(void*)l,
        16, 0, 0);
}

// ---------------- W f32 -> bf16 (2 MB, once per launch; W stays L2-resident) --------
__global__ __launch_bounds__(256)
void w_to_bf16(const float* __restrict__ W, __bf16* __restrict__ Wb) {
    const size_t i = ((size_t)blockIdx.x * 256 + threadIdx.x) * 16;
    f32x4 a0 = *(const f32x4*)(W + i);
    f32x4 a1 = *(const f32x4*)(W + i + 4);
    f32x4 a2 = *(const f32x4*)(W + i + 8);
    f32x4 a3 = *(const f32x4*)(W + i + 12);
    *(bf16x8*)(Wb + i)     = cvt8(a0, a1);
    *(bf16x8*)(Wb + i + 8) = cvt8(a2, a3);
}

// ---------------- 256x256, BK=64, 8-wave, 4-phase/K-tile, fused f32-A GEMM -----------
// LDS buffer (64KB): A kh0 [0,16K) kh1 [16K,32K), B kh0 [32K,48K) kh1 [48K,64K).
// Each 16KB quadrant = 16 MFMA-order 1KB blocks (block bi = rows 16bi..16bi+15;
// lane l <-> row 16bi+(l&15), k-segs (l>>4)*8, byte l*16).
// A (X, f32): reg-staged -- 8 dwordx4 loads -> cvt -> 4 ds_write_b128 (fuses the
// f32->bf16 conversion into the GEMM; no separate convert pass, no Xb traffic).
// B (Wb, bf16, L2-resident): glds16 DMA, per-lane pre-swizzled source.
// Round t (tile t in CUR): P0 stages tile t+1 into OPP (4 B-glds + A ds_writes
// from regs); P1/P2 issue the 8 A-loads for tile t+2; P3 waits vmcnt(8) --
// retires exactly B(t+1), keeps all 8 A-loads in flight (never drains in-loop).
__global__ __launch_bounds__(BDIM, 2)
void fused_linear_act(const float* __restrict__ X,    // [B_ROWS][IN_F] f32
                      const __bf16* __restrict__ Wb,  // [OUT_F][IN_F] bf16
                      const float* __restrict__ bias, // [OUT_F]
                      float* __restrict__ O)          // [B_ROWS][OUT_F]
{
    __shared__ __attribute__((aligned(16))) unsigned char lds[2 * 65536];  // 128 KB

    const int bx  = blockIdx.x;                 // 1024 blocks
    // XCD-aware: 4 consecutive blocks per XCD share one A panel (L2 reuse).
    const int xcd = bx & 7;
    const int idx = bx >> 3;
    const int nt  = idx & 3;
    const int mt  = xcd + 8 * (idx >> 2);
    const int m0 = mt * BM;
    const int n0 = nt * BN;

    const int tid  = threadIdx.x;
    const int lane = tid & 63;
    const int wave = tid >> 6;                  // 0..7, 2M x 4N
    const int wr2  = wave >> 2;                 // m-half of output
    const int w4   = wave & 3;                  // n-quarter of output
    const int lrow = lane & 15;
    const int quad = lane >> 4;

    // A staging: thread -> (row arow, k-half ah); 8 f32x4 loads -> 4 ds_write_b128
    const int arow = tid >> 1;                  // 0..255
    const int ah   = tid & 1;                   // k-half quadrant
    const float* asrc = X + (size_t)(m0 + arow) * IN_F + ah * 32;
    const int awr = ah * 16384 + (arow >> 4) * 1024 + (arow & 15) * 16;

    // B staging source (per-lane, MFMA-order pre-swizzle)
    const __bf16* bgp = Wb + (size_t)(n0 + 32 * wave + lrow) * IN_F + quad * 8;

    unsigned char* const b0 = lds;
    unsigned char* const b1 = lds + 65536;

    f32x4 acc[8][4];
    #pragma unroll
    for (int i = 0; i < 8; ++i)
        #pragma unroll
        for (int j = 0; j < 4; ++j)
            acc[i][j] = (f32x4){0.f, 0.f, 0.f, 0.f};

    f32x4 ar0, ar1, ar2, ar3, ar4, ar5, ar6, ar7;   // A prefetch regs (1 tile)
    bf16x8 aq0, aq1, aq2, aq3, bq0, bq1, bq2, bq3;  // per-phase fragments

#define ALOAD_LO(KA) do { \
    ar0 = *(const f32x4*)(asrc + (KA));      ar1 = *(const f32x4*)(asrc + (KA) + 4);  \
    ar2 = *(const f32x4*)(asrc + (KA) + 8);  ar3 = *(const f32x4*)(asrc + (KA) + 12); } while (0)
#define ALOAD_HI(KA) do { \
    ar4 = *(const f32x4*)(asrc + (KA) + 16); ar5 = *(const f32x4*)(asrc + (KA) + 20); \
    ar6 = *(const f32x4*)(asrc + (KA) + 24); ar7 = *(const f32x4*)(asrc + (KA) + 28); } while (0)
#define DSW(BUF) do { unsigned char* _w = (BUF) + awr; \
    *(bf16x8*)(_w)       = cvt8(ar0, ar1); \
    *(bf16x8*)(_w + 256) = cvt8(ar2, ar3); \
    *(bf16x8*)(_w + 512) = cvt8(ar4, ar5); \
    *(bf16x8*)(_w + 768) = cvt8(ar6, ar7); } while (0)
// all 4 B-glds of one K-tile (kh0 at K, kh1 at K+32)
#define GBALL(BUF, K) do { unsigned char* _d0 = (BUF) + 32768 + wave * 2048; \
    unsigned char* _d1 = _d0 + 16384; \
    glds16(bgp + (K), _d0);      glds16(bgp + (K) + 16 * IN_F, _d0 + 1024); \
    glds16(bgp + (K) + 32, _d1); glds16(bgp + (K) + 32 + 16 * IN_F, _d1 + 1024); } while (0)
#define RA(BUF, KH, MH) do { \
    const unsigned char* _r = (BUF) + (KH) * 16384 + (wr2 * 8 + (MH) * 4) * 1024 + lane * 16; \
    aq0 = *(const bf16x8*)(_r);        aq1 = *(const bf16x8*)(_r + 1024); \
    aq2 = *(const bf16x8*)(_r + 2048); aq3 = *(const bf16x8*)(_r + 3072); } while (0)
#define RB(BUF, KH) do { \
    const unsigned char* _r = (BUF) + 32768 + (KH) * 16384 + (w4 * 4) * 1024 + lane * 16; \
    bq0 = *(const bf16x8*)(_r);        bq1 = *(const bf16x8*)(_r + 1024); \
    bq2 = *(const bf16x8*)(_r + 2048); bq3 = *(const bf16x8*)(_r + 3072); } while (0)
#define MFMA1(MH, I, J) acc[(MH)*4+(I)][(J)] = \
    __builtin_amdgcn_mfma_f32_16x16x32_bf16(aq##I, bq##J, acc[(MH)*4+(I)][(J)], 0, 0, 0)
#define MFMAQ(MH) do { __builtin_amdgcn_s_setprio(1); \
    MFMA1(MH,0,0); MFMA1(MH,0,1); MFMA1(MH,0,2); MFMA1(MH,0,3); \
    MFMA1(MH,1,0); MFMA1(MH,1,1); MFMA1(MH,1,2); MFMA1(MH,1,3); \
    MFMA1(MH,2,0); MFMA1(MH,2,1); MFMA1(MH,2,2); MFMA1(MH,2,3); \
    MFMA1(MH,3,0); MFMA1(MH,3,1); MFMA1(MH,3,2); MFMA1(MH,3,3); \
    __builtin_amdgcn_s_setprio(0); } while (0)
#define BAR() __builtin_amdgcn_s_barrier()
#define VM8() asm volatile("s_waitcnt vmcnt(8)" ::: "memory")
#define VM0() asm volatile("s_waitcnt vmcnt(0)" ::: "memory")
#define VMNONE() ((void)0)

// Round t: tile t in CUR; stage tile t+1 -> OPP at P0 (B-glds + A ds_writes);
// A-loads for tile t+2 at P1/P2; counted wait at P3.
#define ROUND(CUR, OPP, DO_STAGE, KB1, DO_ALOAD, KA2, VMW) do { \
    /* P0 */ if (DO_STAGE) { GBALL(OPP, KB1); DSW(OPP); } \
             RB(CUR, 0); RA(CUR, 0, 0); BAR(); MFMAQ(0); BAR(); \
    /* P1 */ if (DO_ALOAD) ALOAD_LO(KA2); \
             RA(CUR, 0, 1); BAR(); MFMAQ(1); BAR(); \
    /* P2 */ if (DO_ALOAD) ALOAD_HI(KA2); \
             RB(CUR, 1); RA(CUR, 1, 0); BAR(); MFMAQ(0); BAR(); \
    /* P3 */ RA(CUR, 1, 1); BAR(); MFMAQ(1); VMW(); BAR(); \
} while (0)

    // Prologue: A(0) regs -> LDS b0; B(0) glds -> b0; A(1) regs loaded.
    ALOAD_LO(0); ALOAD_HI(0);
    GBALL(b0, 0);
    DSW(b0);                       // compiler inserts vmcnt for ar* (retires A(0))
    ALOAD_LO(64); ALOAD_HI(64);
    asm volatile("s_waitcnt vmcnt(8) lgkmcnt(0)" ::: "memory");  // retire B(0) glds
    BAR();

    // Steady rounds 0..13: stage B(t+1)+A(t+1)->OPP, load A(t+2).
    #pragma unroll 1
    for (int t = 0; t < 14; t += 2) {
        ROUND(b0, b1, true, (t + 1) * 64, true, (t + 2) * 64, VM8);
        ROUND(b1, b0, true, (t + 2) * 64, true, (t + 3) * 64, VM8);
    }
    // Round 14: stage tile15 (regs hold A(15)); no more A-loads; drain glds.
    ROUND(b0, b1, true, 15 * 64, false, 0, VM0);
    // Round 15: pure compute.
    ROUND(b1, b0, false, 0, false, 0, VMNONE);

    // Epilogue: bias + cyclic activation; selector = col%4 = lane&3 (branchless)
    const int s = lane & 3;
    const float kmul = (s == 0) ? -2.f : -1.f;
    const float aa   = (s == 0) ?  2.f :  1.f;
    const float cc   = (s == 0) ? -1.f :  0.f;
    const bool  is_sin  = (s == 1);
    const bool  is_relu = (s == 2);

    float bv[4];
    #pragma unroll
    for (int fn = 0; fn < 4; ++fn) bv[fn] = bias[n0 + w4 * 64 + fn * 16 + lrow];

    #pragma unroll
    for (int fm = 0; fm < 8; ++fm) {
        #pragma unroll
        for (int r = 0; r < 4; ++r) {
            const int gr = m0 + wr2 * 128 + fm * 16 + quad * 4 + r;
            float* op = O + (size_t)gr * OUT_F + n0 + w4 * 64 + lrow;
            #pragma unroll
            for (int fn = 0; fn < 4; ++fn) {
                const float y = acc[fm][fn][r] + bv[fn];
                const float e = __expf(kmul * y);
                const float g = fmaf(aa, __builtin_amdgcn_rcpf(1.f + e), cc);
                const float sv = __sinf(y);
                const float rv = fmaxf(y, 0.f);
                const float res = is_sin ? sv : (is_relu ? rv : g);
                op[fn * 16] = res;
            }
        }
    }
}

extern "C" void kernel_launch(void* const* d_in, const int* in_sizes, int n_in,
                              void* d_out, int out_size, void* d_ws, size_t ws_size,
                              hipStream_t stream) {
    const float* X = (const float*)d_in[0];
    const float* W = (const float*)d_in[1];
    const float* b = (const float*)d_in[2];
    float* O = (float*)d_out;
    __bf16* Wb = (__bf16*)d_ws;   // 2 MB workspace for bf16 W

    const size_t nW = (size_t)OUT_F * IN_F;
    w_to_bf16<<<(int)(nW / (256 * 16)), 256, 0, stream>>>(W, Wb);

    const int grid = (B_ROWS / BM) * (OUT_F / BN);  // 1024 blocks
    fused_linear_act<<<grid, BDIM, 0, stream>>>(X, Wb, b, O);
}

// Round 6
// 590.658 us; speedup vs baseline: 1.0391x; 1.0391x over previous
//
#include <hip/hip_runtime.h>

// Problem constants (fixed by reference)
constexpr int B_ROWS = 65536;
constexpr int IN_F   = 1024;
constexpr int OUT_F  = 1024;

constexpr int BDIM = 512;            // 8 waves
constexpr int BM = 256, BN = 256, BK = 64;

typedef __bf16 bf16x8 __attribute__((ext_vector_type(8)));
typedef float  f32x4  __attribute__((ext_vector_type(4)));

__device__ __forceinline__ bf16x8 cvt8(f32x4 u0, f32x4 u1) {
    bf16x8 v;
    v[0] = (__bf16)u0[0]; v[1] = (__bf16)u0[1]; v[2] = (__bf16)u0[2]; v[3] = (__bf16)u0[3];
    v[4] = (__bf16)u1[0]; v[5] = (__bf16)u1[1]; v[6] = (__bf16)u1[2]; v[7] = (__bf16)u1[3];
    return v;
}

__device__ __forceinline__ void glds16(const __bf16* g, unsigned char* l) {
    __builtin_amdgcn_global_load_lds(
        (const __attribute__((address_space(1))) unsigned int*)(const void*)g,
        (__attribute__((address_space(3))) unsigned int*)(void*)l,
        16, 0, 0);
}

// ---------------- converts ----------------------------------------------------------
__global__ __launch_bounds__(256)
void w_to_bf16(const float* __restrict__ W, __bf16* __restrict__ Wb) {
    const size_t i = ((size_t)blockIdx.x * 256 + threadIdx.x) * 16;
    f32x4 a0 = *(const f32x4*)(W + i);
    f32x4 a1 = *(const f32x4*)(W + i + 4);
    f32x4 a2 = *(const f32x4*)(W + i + 8);
    f32x4 a3 = *(const f32x4*)(W + i + 12);
    *(bf16x8*)(Wb + i)     = cvt8(a0, a1);
    *(bf16x8*)(Wb + i + 8) = cvt8(a2, a3);
}

// converts X rows [32768, 65536) into Xb at GLOBAL row index
__global__ __launch_bounds__(256)
void cvt_half(const float* __restrict__ X, __bf16* __restrict__ Xb) {
    const size_t i = (size_t)32768 * IN_F + ((size_t)blockIdx.x * 256 + threadIdx.x) * 16;
    f32x4 a0 = *(const f32x4*)(X + i);
    f32x4 a1 = *(const f32x4*)(X + i + 4);
    f32x4 a2 = *(const f32x4*)(X + i + 8);
    f32x4 a3 = *(const f32x4*)(X + i + 12);
    *(bf16x8*)(Xb + i)     = cvt8(a0, a1);
    *(bf16x8*)(Xb + i + 8) = cvt8(a2, a3);
}

// ---------------- shared fragment/MFMA/epilogue machinery ----------------------------
#define RA(BUF, KH, MH) do { \
    const unsigned char* _r = (BUF) + (KH) * 16384 + (wr2 * 8 + (MH) * 4) * 1024 + lane * 16; \
    aq0 = *(const bf16x8*)(_r);        aq1 = *(const bf16x8*)(_r + 1024); \
    aq2 = *(const bf16x8*)(_r + 2048); aq3 = *(const bf16x8*)(_r + 3072); } while (0)
#define RB(BUF, KH) do { \
    const unsigned char* _r = (BUF) + 32768 + (KH) * 16384 + (w4 * 4) * 1024 + lane * 16; \
    bq0 = *(const bf16x8*)(_r);        bq1 = *(const bf16x8*)(_r + 1024); \
    bq2 = *(const bf16x8*)(_r + 2048); bq3 = *(const bf16x8*)(_r + 3072); } while (0)
#define MFMA1(MH, I, J) acc[(MH)*4+(I)][(J)] = \
    __builtin_amdgcn_mfma_f32_16x16x32_bf16(aq##I, bq##J, acc[(MH)*4+(I)][(J)], 0, 0, 0)
#define MFMAQ(MH) do { __builtin_amdgcn_s_setprio(1); \
    MFMA1(MH,0,0); MFMA1(MH,0,1); MFMA1(MH,0,2); MFMA1(MH,0,3); \
    MFMA1(MH,1,0); MFMA1(MH,1,1); MFMA1(MH,1,2); MFMA1(MH,1,3); \
    MFMA1(MH,2,0); MFMA1(MH,2,1); MFMA1(MH,2,2); MFMA1(MH,2,3); \
    MFMA1(MH,3,0); MFMA1(MH,3,1); MFMA1(MH,3,2); MFMA1(MH,3,3); \
    __builtin_amdgcn_s_setprio(0); } while (0)
#define BAR() __builtin_amdgcn_s_barrier()
#define VM8() asm volatile("s_waitcnt vmcnt(8)" ::: "memory")
#define VM4() asm volatile("s_waitcnt vmcnt(4)" ::: "memory")
#define VM0() asm volatile("s_waitcnt vmcnt(0)" ::: "memory")
#define VMNONE() ((void)0)

// epilogue: bias + cyclic activation; selector = col%4 = lane&3 (branchless)
#define EPILOGUE() do { \
    const int s = lane & 3; \
    const float kmul = (s == 0) ? -2.f : -1.f; \
    const float aa   = (s == 0) ?  2.f :  1.f; \
    const float cc   = (s == 0) ? -1.f :  0.f; \
    const bool  is_sin  = (s == 1); \
    const bool  is_relu = (s == 2); \
    float bv[4]; \
    _Pragma("unroll") \
    for (int fn = 0; fn < 4; ++fn) bv[fn] = bias[n0 + w4 * 64 + fn * 16 + lrow]; \
    _Pragma("unroll") \
    for (int fm = 0; fm < 8; ++fm) { \
        _Pragma("unroll") \
        for (int r = 0; r < 4; ++r) { \
            const int gr = m0 + wr2 * 128 + fm * 16 + quad * 4 + r; \
            float* op = O + (size_t)gr * OUT_F + n0 + w4 * 64 + lrow; \
            _Pragma("unroll") \
            for (int fn = 0; fn < 4; ++fn) { \
                const float y = acc[fm][fn][r] + bv[fn]; \
                const float e = __expf(kmul * y); \
                const float g = fmaf(aa, __builtin_amdgcn_rcpf(1.f + e), cc); \
                const float sv = __sinf(y); \
                const float rv = fmaxf(y, 0.f); \
                const float res = is_sin ? sv : (is_relu ? rv : g); \
                op[fn * 16] = res; \
            } \
        } \
    } \
} while (0)

// ================= ARM A: fused f32-A GEMM, ALOAD@P0 (4-phase reg cover) =============
__global__ __launch_bounds__(BDIM, 2)
void fused_v2(const float* __restrict__ X, const __bf16* __restrict__ Wb,
              const float* __restrict__ bias, float* __restrict__ O, int m_base)
{
    __shared__ __attribute__((aligned(16))) unsigned char lds[2 * 65536];

    const int bx  = blockIdx.x;
    const int xcd = bx & 7;
    const int idx = bx >> 3;
    const int nt  = idx & 3;
    const int mtl = xcd + 8 * (idx >> 2);
    const int m0 = m_base + mtl * BM;
    const int n0 = nt * BN;

    const int tid  = threadIdx.x;
    const int lane = tid & 63;
    const int wave = tid >> 6;
    const int wr2  = wave >> 2;
    const int w4   = wave & 3;
    const int lrow = lane & 15;
    const int quad = lane >> 4;

    const int arow = tid >> 1;
    const int ah   = tid & 1;
    const float* asrc = X + (size_t)(m0 + arow) * IN_F + ah * 32;
    const int awr = ah * 16384 + (arow >> 4) * 1024 + (arow & 15) * 16;

    const __bf16* bgp = Wb + (size_t)(n0 + 32 * wave + lrow) * IN_F + quad * 8;

    unsigned char* const b0 = lds;
    unsigned char* const b1 = lds + 65536;

    f32x4 acc[8][4];
    #pragma unroll
    for (int i = 0; i < 8; ++i)
        #pragma unroll
        for (int j = 0; j < 4; ++j)
            acc[i][j] = (f32x4){0.f, 0.f, 0.f, 0.f};

    f32x4 ar0, ar1, ar2, ar3, ar4, ar5, ar6, ar7;
    bf16x8 aq0, aq1, aq2, aq3, bq0, bq1, bq2, bq3;

#define ALOAD_LO(KA) do { \
    ar0 = *(const f32x4*)(asrc + (KA));      ar1 = *(const f32x4*)(asrc + (KA) + 4);  \
    ar2 = *(const f32x4*)(asrc + (KA) + 8);  ar3 = *(const f32x4*)(asrc + (KA) + 12); } while (0)
#define ALOAD_HI(KA) do { \
    ar4 = *(const f32x4*)(asrc + (KA) + 16); ar5 = *(const f32x4*)(asrc + (KA) + 20); \
    ar6 = *(const f32x4*)(asrc + (KA) + 24); ar7 = *(const f32x4*)(asrc + (KA) + 28); } while (0)
#define DSW(BUF) do { unsigned char* _w = (BUF) + awr; \
    *(bf16x8*)(_w)       = cvt8(ar0, ar1); \
    *(bf16x8*)(_w + 256) = cvt8(ar2, ar3); \
    *(bf16x8*)(_w + 512) = cvt8(ar4, ar5); \
    *(bf16x8*)(_w + 768) = cvt8(ar6, ar7); } while (0)
#define GBALL(BUF, K) do { unsigned char* _d0 = (BUF) + 32768 + wave * 2048; \
    unsigned char* _d1 = _d0 + 16384; \
    glds16(bgp + (K), _d0);      glds16(bgp + (K) + 16 * IN_F, _d0 + 1024); \
    glds16(bgp + (K) + 32, _d1); glds16(bgp + (K) + 32 + 16 * IN_F, _d1 + 1024); } while (0)

// Round t: tile t in CUR. P0: stage tile t+1 -> OPP (B glds + A ds_writes from
// regs loaded LAST round's P0 = 4-phase cover) + issue A-loads for tile t+2.
#define FROUND(CUR, OPP, DO_STAGE, KB1, DO_ALOAD, KA2, VMW) do { \
    if (DO_STAGE) { GBALL(OPP, KB1); DSW(OPP); } \
    if (DO_ALOAD) { ALOAD_LO(KA2); ALOAD_HI(KA2); __builtin_amdgcn_sched_barrier(0); } \
    RB(CUR, 0); RA(CUR, 0, 0); BAR(); MFMAQ(0); BAR(); \
    RA(CUR, 0, 1); BAR(); MFMAQ(1); BAR(); \
    RB(CUR, 1); RA(CUR, 1, 0); BAR(); MFMAQ(0); BAR(); \
    RA(CUR, 1, 1); BAR(); MFMAQ(1); VMW(); BAR(); \
} while (0)

    // Prologue: A(0)->b0 (full wait, one-time), B(0) glds, A(1) regs.
    ALOAD_LO(0); ALOAD_HI(0);
    GBALL(b0, 0);
    DSW(b0);
    ALOAD_LO(64); ALOAD_HI(64);
    asm volatile("s_waitcnt vmcnt(8) lgkmcnt(0)" ::: "memory");  // retire B(0)
    BAR();

    #pragma unroll 1
    for (int t = 0; t < 14; t += 2) {
        FROUND(b0, b1, true, (t + 1) * 64, true, (t + 2) * 64, VM8);
        FROUND(b1, b0, true, (t + 2) * 64, true, (t + 3) * 64, VM8);
    }
    FROUND(b0, b1, true, 15 * 64, false, 0, VM0);   // stage tile15 (regs hold A15)
    FROUND(b1, b0, false, 0, false, 0, VMNONE);     // pure compute

    EPILOGUE();
#undef ALOAD_LO
#undef ALOAD_HI
#undef DSW
#undef GBALL
#undef FROUND
}

// ================= ARM B: control — round-4 glds-only GEMM (bf16 Xb) =================
__global__ __launch_bounds__(BDIM, 2)
void gemm_split(const __bf16* __restrict__ Xb, const __bf16* __restrict__ Wb,
                const float* __restrict__ bias, float* __restrict__ O, int m_base)
{
    __shared__ __attribute__((aligned(16))) unsigned char lds[2 * 65536];

    const int bx  = blockIdx.x;
    const int xcd = bx & 7;
    const int idx = bx >> 3;
    const int nt  = idx & 3;
    const int mtl = xcd + 8 * (idx >> 2);
    const int m0 = m_base + mtl * BM;
    const int n0 = nt * BN;

    const int tid  = threadIdx.x;
    const int lane = tid & 63;
    const int wave = tid >> 6;
    const int wr2  = wave >> 2;
    const int w4   = wave & 3;
    const int lrow = lane & 15;
    const int quad = lane >> 4;

    const __bf16* agp = Xb + (size_t)(m0 + 32 * wave + lrow) * IN_F + quad * 8;
    const __bf16* bgp = Wb + (size_t)(n0 + 32 * wave + lrow) * IN_F + quad * 8;

    unsigned char* const b0 = lds;
    unsigned char* const b1 = lds + 65536;

    f32x4 acc[8][4];
    #pragma unroll
    for (int i = 0; i < 8; ++i)
        #pragma unroll
        for (int j = 0; j < 4; ++j)
            acc[i][j] = (f32x4){0.f, 0.f, 0.f, 0.f};

    bf16x8 aq0, aq1, aq2, aq3, bq0, bq1, bq2, bq3;

#define GA(BUF, KH, K) do { unsigned char* _d = (BUF) + (KH) * 16384 + wave * 2048; \
    glds16(agp + (K), _d); glds16(agp + (K) + 16 * IN_F, _d + 1024); } while (0)
#define GB(BUF, KH, K) do { unsigned char* _d = (BUF) + 32768 + (KH) * 16384 + wave * 2048; \
    glds16(bgp + (K), _d); glds16(bgp + (K) + 16 * IN_F, _d + 1024); } while (0)
#define SROUND(CUR, OPP, KT) do { \
    GA(OPP, 1, ((KT) + 1) * 64 + 32); RB(CUR, 0); RA(CUR, 0, 0); \
             BAR(); MFMAQ(0); BAR(); \
    GB(OPP, 1, ((KT) + 1) * 64 + 32); RA(CUR, 0, 1); \
             BAR(); MFMAQ(1); BAR(); \
    GA(CUR, 0, ((KT) + 2) * 64); RB(CUR, 1); RA(CUR, 1, 0); \
             BAR(); MFMAQ(0); BAR(); \
    GB(CUR, 0, ((KT) + 2) * 64); RA(CUR, 1, 1); \
             BAR(); MFMAQ(1); VM4(); BAR(); \
} while (0)

    GA(b0, 0, 0);  GB(b0, 0, 0);
    GA(b0, 1, 32); GB(b0, 1, 32);
    GA(b1, 0, 64); GB(b1, 0, 64);
    VM4();
    BAR();

    #pragma unroll 1
    for (int kt = 0; kt < 14; kt += 2) {
        SROUND(b0, b1, kt);
        SROUND(b1, b0, kt + 1);
    }
    GA(b1, 1, 15 * 64 + 32); RB(b0, 0); RA(b0, 0, 0); BAR(); MFMAQ(0); BAR();
    GB(b1, 1, 15 * 64 + 32); RA(b0, 0, 1);            BAR(); MFMAQ(1); BAR();
    RB(b0, 1); RA(b0, 1, 0);                          BAR(); MFMAQ(0); BAR();
    RA(b0, 1, 1);                                     BAR(); MFMAQ(1); VM0(); BAR();
    RB(b1, 0); RA(b1, 0, 0); BAR(); MFMAQ(0); BAR();
    RA(b1, 0, 1);            BAR(); MFMAQ(1); BAR();
    RB(b1, 1); RA(b1, 1, 0); BAR(); MFMAQ(0); BAR();
    RA(b1, 1, 1);            BAR(); MFMAQ(1);

    EPILOGUE();
#undef GA
#undef GB
#undef SROUND
}

extern "C" void kernel_launch(void* const* d_in, const int* in_sizes, int n_in,
                              void* d_out, int out_size, void* d_ws, size_t ws_size,
                              hipStream_t stream) {
    const float* X = (const float*)d_in[0];
    const float* W = (const float*)d_in[1];
    const float* b = (const float*)d_in[2];
    float* O = (float*)d_out;

    const size_t nX = (size_t)B_ROWS * IN_F;
    const size_t nW = (size_t)OUT_F * IN_F;
    __bf16* Wb = (__bf16*)d_ws;                       // 2 MB
    __bf16* Xb = (__bf16*)d_ws + nW;                  // 128 MB (half2 filled)

    w_to_bf16<<<(int)(nW / (256 * 16)), 256, 0, stream>>>(W, Wb);

    if (ws_size >= (nW + nX) * sizeof(__bf16)) {
        // ARM A: fused f32-A GEMM on rows [0, 32768)
        fused_v2<<<512, BDIM, 0, stream>>>(X, Wb, b, O, 0);
        // ARM B: convert + glds-only GEMM on rows [32768, 65536)
        cvt_half<<<(int)((nX / 2) / (256 * 16)), 256, 0, stream>>>(X, Xb);
        gemm_split<<<512, BDIM, 0, stream>>>(Xb, Wb, b, O, 32768);
    } else {
        // ws too small for Xb: fused everywhere
        fused_v2<<<1024, BDIM, 0, stream>>>(X, Wb, b, O, 0);
    }
}

// Round 7
// 590.399 us; speedup vs baseline: 1.0396x; 1.0004x over previous
//
#include <hip/hip_runtime.h>

// Problem constants (fixed by reference)
constexpr int B_ROWS = 65536;
constexpr int IN_F   = 1024;
constexpr int OUT_F  = 1024;

constexpr int BDIM = 512;            // 8 waves, 4M x 2N
constexpr int BM = 256, BN = 256, BK = 32;

typedef __bf16 bf16x8 __attribute__((ext_vector_type(8)));
typedef float  f32x4  __attribute__((ext_vector_type(4)));

__device__ __forceinline__ bf16x8 cvt8(f32x4 u0, f32x4 u1) {
    bf16x8 v;
    v[0] = (__bf16)u0[0]; v[1] = (__bf16)u0[1]; v[2] = (__bf16)u0[2]; v[3] = (__bf16)u0[3];
    v[4] = (__bf16)u1[0]; v[5] = (__bf16)u1[1]; v[6] = (__bf16)u1[2]; v[7] = (__bf16)u1[3];
    return v;
}

// async global->LDS, 16B per lane (wave stages 1KB contiguous at uniform lds base)
__device__ __forceinline__ void glds16(const void* g, unsigned char* l) {
    __builtin_amdgcn_global_load_lds(
        (const __attribute__((address_space(1))) unsigned int*)g,
        (__attribute__((address_space(3))) unsigned int*)(void*)l,
        16, 0, 0);
}

// ---------------- W f32 -> bf16 (2 MB, once per launch; W stays L2-resident) --------
__global__ __launch_bounds__(256)
void w_to_bf16(const float* __restrict__ W, __bf16* __restrict__ Wb) {
    const size_t i = ((size_t)blockIdx.x * 256 + threadIdx.x) * 16;
    f32x4 a0 = *(const f32x4*)(W + i);
    f32x4 a1 = *(const f32x4*)(W + i + 4);
    f32x4 a2 = *(const f32x4*)(W + i + 8);
    f32x4 a3 = *(const f32x4*)(W + i + 12);
    *(bf16x8*)(Wb + i)     = cvt8(a0, a1);
    *(bf16x8*)(Wb + i + 8) = cvt8(a2, a3);
}

// ---------------- 256x256, BK=32, f32-A-in-LDS, 3-buffer, 2-phase rounds -------------
// Buffer (48KB): A-f32 [0,32K): 16 row-blocks x 2KB; block bi layout:
//   unit(row=l&15, u=kq*2+half) at bi*2048 + u*256 + row*16  (u=0..7, 16B of 4 f32)
//   -> glds g of block bi writes u = g*4 + (lane>>4), src = per-lane pre-swizzle.
// B-bf16 [32K,48K): 16 col-blocks x 1KB; block ci: unit(col=l&15, kq=l>>4) at
//   ci*1024 + kq*256 + col*16  == the exact MFMA B-fragment order.
// A fragments are read as 2x ds_read_b128 (f32) + cvt8 -> bf16x8: the f32->bf16
// conversion is fused into the GEMM at ~32 VALU/wave/round (no separate pass).
// Waves 4M x 2N (A-redundancy 2, B-redundancy 4: puts re-reads on the bf16 side).
// Round t: compute tile t from buf[t%3]; stage tile t+2 -> buf[(t+2)%3] (3 glds
// per phase); end-of-round vmcnt(6) retires tile t+1, keeps t+2's 6 in flight.
__global__ __launch_bounds__(BDIM, 2)
void fused_linear_act(const float* __restrict__ X,    // [B_ROWS][IN_F] f32
                      const __bf16* __restrict__ Wb,  // [OUT_F][IN_F] bf16
                      const float* __restrict__ bias, // [OUT_F]
                      float* __restrict__ O)          // [B_ROWS][OUT_F]
{
    __shared__ __attribute__((aligned(16))) unsigned char lds[3 * 49152];  // 144 KB

    const int bx  = blockIdx.x;                 // 1024 blocks
    const int xcd = bx & 7;
    const int idx = bx >> 3;
    const int nt  = idx & 3;
    const int mt  = xcd + 8 * (idx >> 2);
    const int m0 = mt * BM;
    const int n0 = nt * BN;

    const int tid  = threadIdx.x;
    const int lane = tid & 63;
    const int wave = tid >> 6;                  // 0..7
    const int wr4  = wave >> 1;                 // m-quarter (64 rows)
    const int wn2  = wave & 1;                  // n-half (128 cols)
    const int lrow = lane & 15;
    const int quad = lane >> 4;

    // per-lane pre-swizzled staging sources
    const float*  agp = X  + (size_t)(m0 + lrow) * IN_F + quad * 4;   // f32
    const __bf16* bgp = Wb + (size_t)(n0 + lrow) * IN_F + quad * 8;   // bf16
    const int bi0 = 2 * wave, bi1 = 2 * wave + 1;    // this wave's A row-blocks
    const int ci0 = 2 * wave, ci1 = 2 * wave + 1;    // this wave's B col-blocks

    unsigned char* const b0 = lds;
    unsigned char* const b1 = lds + 49152;
    unsigned char* const b2 = lds + 98304;

    f32x4 acc[4][8];
    #pragma unroll
    for (int i = 0; i < 4; ++i)
        #pragma unroll
        for (int j = 0; j < 8; ++j)
            acc[i][j] = (f32x4){0.f, 0.f, 0.f, 0.f};

    bf16x8 aq0, aq1, aq2, aq3, bq0, bq1, bq2, bq3;

// A glds: block BI, part G (covers u = G*4 + quad), tile k-offset K (f32 elems)
#define GA(BUF, BI, G, K) \
    glds16(agp + (size_t)(BI) * 16384 + (G) * 16 + (K), (BUF) + (BI) * 2048 + (G) * 1024)
// B glds: block CI, tile k-offset K (bf16 elems)
#define GB(BUF, CI, K) \
    glds16(bgp + (size_t)(CI) * 16384 + (K), (BUF) + 32768 + (CI) * 1024)
// all 4 A fragments of this wave's 64 rows (f32 read + cvt), once per round
#define RAALL(BUF) do { \
    const unsigned char* _p = (BUF) + (wr4 * 4) * 2048 + quad * 512 + lrow * 16; \
    f32x4 _h0, _h1; \
    _h0 = *(const f32x4*)(_p);        _h1 = *(const f32x4*)(_p + 256);        aq0 = cvt8(_h0, _h1); \
    _h0 = *(const f32x4*)(_p + 2048); _h1 = *(const f32x4*)(_p + 2048 + 256); aq1 = cvt8(_h0, _h1); \
    _h0 = *(const f32x4*)(_p + 4096); _h1 = *(const f32x4*)(_p + 4096 + 256); aq2 = cvt8(_h0, _h1); \
    _h0 = *(const f32x4*)(_p + 6144); _h1 = *(const f32x4*)(_p + 6144 + 256); aq3 = cvt8(_h0, _h1); \
} while (0)
// 4 B fragments of n-half NH (reloads bq0..3 each phase)
#define RBH(BUF, NH) do { \
    const unsigned char* _r = (BUF) + 32768 + (wn2 * 8 + (NH) * 4) * 1024 + lane * 16; \
    bq0 = *(const bf16x8*)(_r);        bq1 = *(const bf16x8*)(_r + 1024); \
    bq2 = *(const bf16x8*)(_r + 2048); bq3 = *(const bf16x8*)(_r + 3072); } while (0)
#define MFMA1(NH, I, J) acc[(I)][(NH)*4+(J)] = \
    __builtin_amdgcn_mfma_f32_16x16x32_bf16(aq##I, bq##J, acc[(I)][(NH)*4+(J)], 0, 0, 0)
#define MFMAQ(NH) do { __builtin_amdgcn_s_setprio(1); \
    MFMA1(NH,0,0); MFMA1(NH,0,1); MFMA1(NH,0,2); MFMA1(NH,0,3); \
    MFMA1(NH,1,0); MFMA1(NH,1,1); MFMA1(NH,1,2); MFMA1(NH,1,3); \
    MFMA1(NH,2,0); MFMA1(NH,2,1); MFMA1(NH,2,2); MFMA1(NH,2,3); \
    MFMA1(NH,3,0); MFMA1(NH,3,1); MFMA1(NH,3,2); MFMA1(NH,3,3); \
    __builtin_amdgcn_s_setprio(0); } while (0)
#define BAR() __builtin_amdgcn_s_barrier()
#define VM6() asm volatile("s_waitcnt vmcnt(6)" ::: "memory")
#define VM0() asm volatile("s_waitcnt vmcnt(0)" ::: "memory")
#define VMNONE() ((void)0)

// Round: compute tile from CUR; stage tile-at-KT2 into NXT (3 glds per phase).
// End-of-round VMW: vmcnt(6) retires the previous round's staging (next tile),
// leaves this round's 6 glds (tile+2) in flight across the barrier.
#define RND(CUR, NXT, DO_G, KT2, VMW) do { \
    /* P0 */ if (DO_G) { GA(NXT, bi0, 0, KT2); GA(NXT, bi0, 1, KT2); GB(NXT, ci0, KT2); } \
             RAALL(CUR); RBH(CUR, 0); \
             BAR(); MFMAQ(0); BAR(); \
    /* P1 */ if (DO_G) { GA(NXT, bi1, 0, KT2); GA(NXT, bi1, 1, KT2); GB(NXT, ci1, KT2); } \
             RBH(CUR, 1); \
             BAR(); MFMAQ(1); VMW(); BAR(); \
} while (0)

    // Prologue: tile0 -> b0 (6 glds), tile1 -> b1 (6); retire tile0, keep tile1.
    GA(b0, bi0, 0, 0);  GA(b0, bi0, 1, 0);  GB(b0, ci0, 0);
    GA(b0, bi1, 0, 0);  GA(b0, bi1, 1, 0);  GB(b0, ci1, 0);
    GA(b1, bi0, 0, 32); GA(b1, bi0, 1, 32); GB(b1, ci0, 32);
    GA(b1, bi1, 0, 32); GA(b1, bi1, 1, 32); GB(b1, ci1, 32);
    VM6();
    BAR();

    // Rounds 0..29: compute tile r, stage tile r+2.
    #pragma unroll 1
    for (int r = 0; r < 30; r += 3) {
        RND(b0, b2, true, (r + 2) * 32, VM6);
        RND(b1, b0, true, (r + 3) * 32, VM6);
        RND(b2, b1, true, (r + 4) * 32, VM6);
    }
    // Round 30 (tile30 in b0): no staging; drain tile31's 6 glds (1-round old).
    RND(b0, b1, false, 0, VM0);
    // Round 31 (tile31 in b1): pure compute.
    RND(b1, b0, false, 0, VMNONE);

    // Epilogue: bias + cyclic activation; selector = col%4 = lane&3 (branchless)
    const int s = lane & 3;
    const float kmul = (s == 0) ? -2.f : -1.f;
    const float aa   = (s == 0) ?  2.f :  1.f;
    const float cc   = (s == 0) ? -1.f :  0.f;
    const bool  is_sin  = (s == 1);
    const bool  is_relu = (s == 2);

    float bv[8];
    #pragma unroll
    for (int fn = 0; fn < 8; ++fn) bv[fn] = bias[n0 + wn2 * 128 + fn * 16 + lrow];

    #pragma unroll
    for (int fm = 0; fm < 4; ++fm) {
        #pragma unroll
        for (int r = 0; r < 4; ++r) {
            const int gr = m0 + wr4 * 64 + fm * 16 + quad * 4 + r;
            float* op = O + (size_t)gr * OUT_F + n0 + wn2 * 128 + lrow;
            #pragma unroll
            for (int fn = 0; fn < 8; ++fn) {
                const float y = acc[fm][fn][r] + bv[fn];
                const float e = __expf(kmul * y);
                const float g = fmaf(aa, __builtin_amdgcn_rcpf(1.f + e), cc);
                const float sv = __sinf(y);
                const float rv = fmaxf(y, 0.f);
                const float res = is_sin ? sv : (is_relu ? rv : g);
                op[fn * 16] = res;
            }
        }
    }
}

extern "C" void kernel_launch(void* const* d_in, const int* in_sizes, int n_in,
                              void* d_out, int out_size, void* d_ws, size_t ws_size,
                              hipStream_t stream) {
    const float* X = (const float*)d_in[0];
    const float* W = (const float*)d_in[1];
    const float* b = (const float*)d_in[2];
    float* O = (float*)d_out;
    __bf16* Wb = (__bf16*)d_ws;   // 2 MB workspace for bf16 W

    const size_t nW = (size_t)OUT_F * IN_F;
    w_to_bf16<<<(int)(nW / (256 * 16)), 256, 0, stream>>>(W, Wb);

    const int grid = (B_ROWS / BM) * (OUT_F / BN);  // 1024 blocks
    fused_linear_act<<<grid, BDIM, 0, stream>>>(X, Wb, b, O);
}